// Round 4
// baseline (1086.668 us; speedup 1.0000x reference)
//
#include <hip/hip_runtime.h>
#include <math.h>

#define C_ 32
#define D_ 48
#define H_ 128
#define W_ 160
#define HW_ (H_*W_)
#define DHW_ (D_*HW_)

// ---------------- small matrix helpers (device, used by 1-thread setup) ----

__device__ __forceinline__ void combine4(const float* p, float* out) {
    #pragma unroll
    for (int i = 0; i < 16; ++i) out[i] = p[i];
    #pragma unroll
    for (int i = 0; i < 3; ++i) {
        #pragma unroll
        for (int j = 0; j < 4; ++j) {
            float s = 0.f;
            #pragma unroll
            for (int k = 0; k < 3; ++k) s += p[16 + i*4 + k] * p[k*4 + j];
            out[i*4 + j] = s;
        }
    }
}

__device__ void inv4(const float* A, float* out) {
    float M[4][8];
    for (int i = 0; i < 4; ++i)
        for (int j = 0; j < 4; ++j) {
            M[i][j] = A[i*4 + j];
            M[i][4 + j] = (i == j) ? 1.f : 0.f;
        }
    for (int c = 0; c < 4; ++c) {
        int piv = c; float best = fabsf(M[c][c]);
        for (int r = c + 1; r < 4; ++r) {
            float a = fabsf(M[r][c]);
            if (a > best) { best = a; piv = r; }
        }
        if (piv != c)
            for (int j = 0; j < 8; ++j) { float t = M[c][j]; M[c][j] = M[piv][j]; M[piv][j] = t; }
        float ip = 1.f / M[c][c];
        for (int j = 0; j < 8; ++j) M[c][j] *= ip;
        for (int r = 0; r < 4; ++r) if (r != c) {
            float f = M[r][c];
            for (int j = 0; j < 8; ++j) M[r][j] -= f * M[c][j];
        }
    }
    for (int i = 0; i < 4; ++i)
        for (int j = 0; j < 4; ++j) out[i*4 + j] = M[i][4 + j];
}

__device__ __forceinline__ void matmul4(const float* A, const float* B, float* Cm) {
    #pragma unroll
    for (int i = 0; i < 4; ++i)
        #pragma unroll
        for (int j = 0; j < 4; ++j) {
            float s = 0.f;
            #pragma unroll
            for (int k = 0; k < 4; ++k) s += A[i*4 + k] * B[k*4 + j];
            Cm[i*4 + j] = s;
        }
}

__global__ void proj_setup_kernel(const float* __restrict__ refp,
                                  const float* __restrict__ sp1,
                                  const float* __restrict__ sp2,
                                  float* __restrict__ proj_out) {
    if (threadIdx.x != 0 || blockIdx.x != 0) return;
    float rc[16], s1[16], s2[16], ri[16], p[16];
    combine4(refp, rc);
    combine4(sp1, s1);
    combine4(sp2, s2);
    inv4(rc, ri);
    for (int v = 0; v < 2; ++v) {
        matmul4(v == 0 ? s1 : s2, ri, p);
        for (int i = 0; i < 3; ++i)
            for (int j = 0; j < 3; ++j) proj_out[v*12 + i*3 + j] = p[i*4 + j];
        for (int i = 0; i < 3; ++i) proj_out[v*12 + 9 + i] = p[i*4 + 3];
    }
}

// ---------------- warp + variance -----------------------------------------

__global__ __launch_bounds__(256) void variance_kernel(
        const float* __restrict__ ref,
        const float* __restrict__ s1g,
        const float* __restrict__ s2g,
        const float* __restrict__ depthv,
        const float* __restrict__ proj,
        float* __restrict__ var) {
    int idx = blockIdx.x * 256 + threadIdx.x;   // < DHW_
    int x = idx % W_;
    int t = idx / W_;
    int y = t % H_;
    float depth = depthv[idx];
    float fx = (float)x, fy = (float)y;

    int off[2][4];
    float wt[2][4];
    #pragma unroll
    for (int v = 0; v < 2; ++v) {
        const float* P = proj + v*12;
        float rx = P[0]*fx + P[1]*fy + P[2];
        float ry = P[3]*fx + P[4]*fy + P[5];
        float rz = P[6]*fx + P[7]*fy + P[8];
        float X = rx*depth + P[9];
        float Y = ry*depth + P[10];
        float Z = rz*depth + P[11];
        float z = (fabsf(Z) < 1e-6f) ? 1e-6f : Z;
        float px = X / z;
        float py = Y / z;
        float x0f = floorf(px), y0f = floorf(py);
        float wx = px - x0f, wy = py - y0f;
        #pragma unroll
        for (int k = 0; k < 4; ++k) {
            float xi = x0f + (float)(k & 1);
            float yi = y0f + (float)(k >> 1);
            bool valid = (xi >= 0.f) && (xi <= (float)(W_-1)) &&
                         (yi >= 0.f) && (yi <= (float)(H_-1));
            int xc = (int)fminf(fmaxf(xi, 0.f), (float)(W_-1));
            int yc = (int)fminf(fmaxf(yi, 0.f), (float)(H_-1));
            off[v][k] = yc * W_ + xc;
            float w = ((k & 1) ? wx : 1.f - wx) * ((k >> 1) ? wy : 1.f - wy);
            wt[v][k] = valid ? w : 0.f;
        }
    }

    int pix = y*W_ + x;
    size_t obase = (size_t)idx;
    const float inv3 = 1.f / 3.f;
    #pragma unroll 4
    for (int c = 0; c < C_; ++c) {
        const float* p1 = s1g + c*HW_;
        const float* p2 = s2g + c*HW_;
        float r = ref[c*HW_ + pix];
        float wv1 = wt[0][0]*p1[off[0][0]] + wt[0][1]*p1[off[0][1]]
                  + wt[0][2]*p1[off[0][2]] + wt[0][3]*p1[off[0][3]];
        float wv2 = wt[1][0]*p2[off[1][0]] + wt[1][1]*p2[off[1][1]]
                  + wt[1][2]*p2[off[1][2]] + wt[1][3]*p2[off[1][3]];
        float s = r + wv1 + wv2;
        float q = r*r + wv1*wv1 + wv2*wv2;
        float m = s * inv3;
        var[(size_t)c*DHW_ + obase] = q*inv3 - m*m;
    }
}

// ---------------- 3D conv, SAME padding, NCDHW ----------------------------
// Block = 32x8 (x,y) plane, TD=4 depth outputs per thread.
// Staging address math hoisted out of the ic loop (precomputed offsets +
// mask floats, branch-free). FMA nest uses 6-value column registers per
// (i,j) tap: 6 ds_reads feed TD*3*OC FMAs. Weights read from the ORIGINAL
// (OC,IC,3,3,3) layout with wave-uniform indices -> s_load scalar path,
// SGPR operand feeds v_fmac directly (no VGPR cost, no extra ws buffers).

template<int IC, int OC, bool RELU>
__global__ __launch_bounds__(256) void conv3d_kernel(
        const float* __restrict__ in,
        const float* __restrict__ wgt,   // (OC, IC, 3,3,3) original layout
        const float* __restrict__ bias,  // (OC)
        float* __restrict__ out) {
    const int TW = 32, TH = 8, TD = 4;
    const int TILE = (TD+2)*(TH+2)*(TW+2);          // 6*10*34 = 2040
    const int tx = threadIdx.x & 31;
    const int ty = threadIdx.x >> 5;
    const int x0 = blockIdx.x * TW;
    const int y0 = blockIdx.y * TH;
    const int d0 = blockIdx.z * TD;

    __shared__ float tile[TILE];

    // ---- precompute staging slots (ic-invariant) ----
    int   goff[8];
    float gmsk[8];
    #pragma unroll
    for (int k = 0; k < 8; ++k) {
        int s = threadIdx.x + k*256;
        int lx = s % (TW+2);
        int lt = s / (TW+2);
        int ly = lt % (TH+2);
        int ld = lt / (TH+2);
        int gx = x0 + lx - 1;
        int gy = y0 + ly - 1;
        int gd = d0 + ld - 1;
        bool ok = (s < TILE) && gx >= 0 && gx < W_ && gy >= 0 && gy < H_
                             && gd >= 0 && gd < D_;
        goff[k] = ok ? (gd*HW_ + gy*W_ + gx) : 0;
        gmsk[k] = ok ? 1.f : 0.f;
    }

    float acc[TD][OC];
    #pragma unroll
    for (int od = 0; od < TD; ++od)
        #pragma unroll
        for (int oc = 0; oc < OC; ++oc) acc[od][oc] = bias[oc];

    for (int ic = 0; ic < IC; ++ic) {
        const float* inc = in + (size_t)ic * DHW_;
        __syncthreads();
        #pragma unroll
        for (int k = 0; k < 8; ++k) {
            int s = threadIdx.x + k*256;
            if (s < TILE) tile[s] = inc[goff[k]] * gmsk[k];
        }
        __syncthreads();

        const float* wic = wgt + ic*27;   // + oc*IC*27 + kd*9 + ij (all const)
        #pragma unroll
        for (int ij = 0; ij < 9; ++ij) {
            const int i = ij / 3, j = ij % 3;
            const int lbase = (ty + i)*(TW+2) + tx + j;
            float vals[TD+2];
            #pragma unroll
            for (int p = 0; p < TD+2; ++p)
                vals[p] = tile[p*(TH+2)*(TW+2) + lbase];
            #pragma unroll
            for (int od = 0; od < TD; ++od)
                #pragma unroll
                for (int kd = 0; kd < 3; ++kd) {
                    float v = vals[od + kd];
                    #pragma unroll
                    for (int oc = 0; oc < OC; ++oc)
                        acc[od][oc] = fmaf(wic[oc*IC*27 + kd*9 + ij],
                                           v, acc[od][oc]);
                }
        }
    }

    #pragma unroll
    for (int od = 0; od < TD; ++od) {
        int obase = (d0 + od)*HW_ + (y0 + ty)*W_ + (x0 + tx);
        #pragma unroll
        for (int oc = 0; oc < OC; ++oc) {
            float r = acc[od][oc];
            if (RELU) r = fmaxf(r, 0.f);
            out[(size_t)oc*DHW_ + obase] = r;
        }
    }
}

// ---------------- softmax over D ------------------------------------------

__global__ __launch_bounds__(256) void softmax_kernel(
        const float* __restrict__ logits, float* __restrict__ out) {
    int pix = blockIdx.x * 256 + threadIdx.x;   // < HW_
    float v[D_];
    float m = -1e30f;
    #pragma unroll
    for (int d = 0; d < D_; ++d) {
        v[d] = logits[d*HW_ + pix];
        m = fmaxf(m, v[d]);
    }
    float s = 0.f;
    #pragma unroll
    for (int d = 0; d < D_; ++d) {
        v[d] = expf(v[d] - m);
        s += v[d];
    }
    float is = 1.f / s;
    #pragma unroll
    for (int d = 0; d < D_; ++d) out[d*HW_ + pix] = v[d] * is;
}

// ---------------- launch ---------------------------------------------------
// ws layout is byte-identical to the round-1 run that PASSED:
//   proj @ ws+0 (256 B) | var: 32*DHW f32 (126 MB) | hid: 8*DHW f32 (31.5 MB)
// Total 157,286,656 B. No extra allocations (round-3's +28.8 KB overflowed
// ws and corrupted adjacent harness buffers -> post-timing divergence).

extern "C" void kernel_launch(void* const* d_in, const int* in_sizes, int n_in,
                              void* d_out, int out_size, void* d_ws, size_t ws_size,
                              hipStream_t stream) {
    const float* ref_fea = (const float*)d_in[0];
    const float* src1    = (const float*)d_in[1];
    const float* src2    = (const float*)d_in[2];
    const float* ref_prj = (const float*)d_in[3];
    const float* src_pr1 = (const float*)d_in[4];
    const float* src_pr2 = (const float*)d_in[5];
    const float* depth   = (const float*)d_in[6];
    const float* w1      = (const float*)d_in[7];
    const float* b1      = (const float*)d_in[8];
    const float* w2      = (const float*)d_in[9];
    const float* b2      = (const float*)d_in[10];
    float* out = (float*)d_out;

    char* ws = (char*)d_ws;
    float* proj   = (float*)ws;                                         // 24 f
    float* var    = (float*)(ws + 256);                                 // 126 MB
    float* hid    = (float*)(ws + 256 + (size_t)C_*DHW_*sizeof(float)); // 31.5 MB
    float* logits = var;  // variance region dead after conv1 -> reuse

    proj_setup_kernel<<<1, 64, 0, stream>>>(ref_prj, src_pr1, src_pr2, proj);

    variance_kernel<<<DHW_/256, 256, 0, stream>>>(ref_fea, src1, src2, depth, proj, var);

    dim3 cgrid(W_/32, H_/8, D_/4);   // 5 x 16 x 12
    conv3d_kernel<32, 8, true ><<<cgrid, 256, 0, stream>>>(var, w1, b1, hid);
    conv3d_kernel< 8, 1, false><<<cgrid, 256, 0, stream>>>(hid, w2, b2, logits);

    softmax_kernel<<<HW_/256, 256, 0, stream>>>(logits, out);
}

// Round 6
// 505.833 us; speedup vs baseline: 2.1483x; 2.1483x over previous
//
#include <hip/hip_runtime.h>
#include <math.h>

#define C_ 32
#define D_ 48
#define H_ 128
#define W_ 160
#define HW_ (H_*W_)
#define DHW_ (D_*HW_)

// ---------------- small matrix helpers (device, used by 1-thread setup) ----

__device__ __forceinline__ void combine4(const float* p, float* out) {
    #pragma unroll
    for (int i = 0; i < 16; ++i) out[i] = p[i];
    #pragma unroll
    for (int i = 0; i < 3; ++i) {
        #pragma unroll
        for (int j = 0; j < 4; ++j) {
            float s = 0.f;
            #pragma unroll
            for (int k = 0; k < 3; ++k) s += p[16 + i*4 + k] * p[k*4 + j];
            out[i*4 + j] = s;
        }
    }
}

__device__ void inv4(const float* A, float* out) {
    float M[4][8];
    for (int i = 0; i < 4; ++i)
        for (int j = 0; j < 4; ++j) {
            M[i][j] = A[i*4 + j];
            M[i][4 + j] = (i == j) ? 1.f : 0.f;
        }
    for (int c = 0; c < 4; ++c) {
        int piv = c; float best = fabsf(M[c][c]);
        for (int r = c + 1; r < 4; ++r) {
            float a = fabsf(M[r][c]);
            if (a > best) { best = a; piv = r; }
        }
        if (piv != c)
            for (int j = 0; j < 8; ++j) { float t = M[c][j]; M[c][j] = M[piv][j]; M[piv][j] = t; }
        float ip = 1.f / M[c][c];
        for (int j = 0; j < 8; ++j) M[c][j] *= ip;
        for (int r = 0; r < 4; ++r) if (r != c) {
            float f = M[r][c];
            for (int j = 0; j < 8; ++j) M[r][j] -= f * M[c][j];
        }
    }
    for (int i = 0; i < 4; ++i)
        for (int j = 0; j < 4; ++j) out[i*4 + j] = M[i][4 + j];
}

__device__ __forceinline__ void matmul4(const float* A, const float* B, float* Cm) {
    #pragma unroll
    for (int i = 0; i < 4; ++i)
        #pragma unroll
        for (int j = 0; j < 4; ++j) {
            float s = 0.f;
            #pragma unroll
            for (int k = 0; k < 4; ++k) s += A[i*4 + k] * B[k*4 + j];
            Cm[i*4 + j] = s;
        }
}

__global__ void proj_setup_kernel(const float* __restrict__ refp,
                                  const float* __restrict__ sp1,
                                  const float* __restrict__ sp2,
                                  float* __restrict__ proj_out) {
    if (threadIdx.x != 0 || blockIdx.x != 0) return;
    float rc[16], s1[16], s2[16], ri[16], p[16];
    combine4(refp, rc);
    combine4(sp1, s1);
    combine4(sp2, s2);
    inv4(rc, ri);
    for (int v = 0; v < 2; ++v) {
        matmul4(v == 0 ? s1 : s2, ri, p);
        for (int i = 0; i < 3; ++i)
            for (int j = 0; j < 3; ++j) proj_out[v*12 + i*3 + j] = p[i*4 + j];
        for (int i = 0; i < 3; ++i) proj_out[v*12 + 9 + i] = p[i*4 + 3];
    }
}

// ---------------- warp + variance -----------------------------------------

__global__ __launch_bounds__(256) void variance_kernel(
        const float* __restrict__ ref,
        const float* __restrict__ s1g,
        const float* __restrict__ s2g,
        const float* __restrict__ depthv,
        const float* __restrict__ proj,
        float* __restrict__ var) {
    int idx = blockIdx.x * 256 + threadIdx.x;   // < DHW_
    int x = idx % W_;
    int t = idx / W_;
    int y = t % H_;
    float depth = depthv[idx];
    float fx = (float)x, fy = (float)y;

    int off[2][4];
    float wt[2][4];
    #pragma unroll
    for (int v = 0; v < 2; ++v) {
        const float* P = proj + v*12;
        float rx = P[0]*fx + P[1]*fy + P[2];
        float ry = P[3]*fx + P[4]*fy + P[5];
        float rz = P[6]*fx + P[7]*fy + P[8];
        float X = rx*depth + P[9];
        float Y = ry*depth + P[10];
        float Z = rz*depth + P[11];
        float z = (fabsf(Z) < 1e-6f) ? 1e-6f : Z;
        float px = X / z;
        float py = Y / z;
        float x0f = floorf(px), y0f = floorf(py);
        float wx = px - x0f, wy = py - y0f;
        #pragma unroll
        for (int k = 0; k < 4; ++k) {
            float xi = x0f + (float)(k & 1);
            float yi = y0f + (float)(k >> 1);
            bool valid = (xi >= 0.f) && (xi <= (float)(W_-1)) &&
                         (yi >= 0.f) && (yi <= (float)(H_-1));
            int xc = (int)fminf(fmaxf(xi, 0.f), (float)(W_-1));
            int yc = (int)fminf(fmaxf(yi, 0.f), (float)(H_-1));
            off[v][k] = yc * W_ + xc;
            float w = ((k & 1) ? wx : 1.f - wx) * ((k >> 1) ? wy : 1.f - wy);
            wt[v][k] = valid ? w : 0.f;
        }
    }

    int pix = y*W_ + x;
    size_t obase = (size_t)idx;
    const float inv3 = 1.f / 3.f;
    #pragma unroll 4
    for (int c = 0; c < C_; ++c) {
        const float* p1 = s1g + c*HW_;
        const float* p2 = s2g + c*HW_;
        float r = ref[c*HW_ + pix];
        float wv1 = wt[0][0]*p1[off[0][0]] + wt[0][1]*p1[off[0][1]]
                  + wt[0][2]*p1[off[0][2]] + wt[0][3]*p1[off[0][3]];
        float wv2 = wt[1][0]*p2[off[1][0]] + wt[1][1]*p2[off[1][1]]
                  + wt[1][2]*p2[off[1][2]] + wt[1][3]*p2[off[1][3]];
        float s = r + wv1 + wv2;
        float q = r*r + wv1*wv1 + wv2*wv2;
        float m = s * inv3;
        var[(size_t)c*DHW_ + obase] = q*inv3 - m*m;
    }
}

// ---------------- 3D conv, SAME padding, NCDHW ----------------------------
// Block = 32x8 (x,y) plane, TD=8 depth outputs per thread (grid 5x16x6).
// Round-0 conv structure (proven 320us at TD=4) with ONE mechanism change:
// weights are staged ONCE per block into LDS, transposed to [ic*27+tap][oc]
// (oc contiguous, 32B-aligned for OC=8). Weight reads in the FMA nest are
// wave-uniform LDS addresses -> broadcast (free, m136) on the LDS pipe.
// This removes the round-3 hazard where weight loads fell onto per-lane
// VMEM + address-VALU (the 3x regression: VALUBusy 78% but 3x slower).
// TD=8 doubles FMAs per staged byte and per weight read (1:8 wgt:FMA).

template<int IC, int OC, bool RELU>
__global__ __launch_bounds__(256) void conv3d_kernel(
        const float* __restrict__ in,
        const float* __restrict__ wgt,   // (OC, IC, 3,3,3) original layout
        const float* __restrict__ bias,  // (OC)
        float* __restrict__ out) {
    const int TW = 32, TH = 8, TD = 8;
    const int TILE = (TD+2)*(TH+2)*(TW+2);          // 10*10*34 = 3400
    const int NW = IC*27*OC;                        // conv1 6912, conv2 216
    const int tx = threadIdx.x & 31;
    const int ty = threadIdx.x >> 5;
    const int x0 = blockIdx.x * TW;
    const int y0 = blockIdx.y * TH;
    const int d0 = blockIdx.z * TD;

    __shared__ float tile[TILE];
    __shared__ float wlds[NW];

    // one-time: stage weights transposed -> wlds[(ic*27 + tap)*OC + oc]
    for (int t = threadIdx.x; t < NW; t += 256) {
        int oc = t % OC;
        int g  = t / OC;          // ic*27 + tap
        int ic = g / 27;
        int r  = g % 27;
        wlds[t] = wgt[(oc*IC + ic)*27 + r];
    }
    // (visibility guaranteed by the __syncthreads() at top of first ic iter)

    float acc[TD][OC];
    #pragma unroll
    for (int od = 0; od < TD; ++od)
        #pragma unroll
        for (int oc = 0; oc < OC; ++oc) acc[od][oc] = bias[oc];

    for (int ic = 0; ic < IC; ++ic) {
        const float* inc = in + (size_t)ic * DHW_;
        __syncthreads();
        for (int li = threadIdx.x; li < TILE; li += 256) {
            int lx = li % (TW+2);
            int lt = li / (TW+2);
            int ly = lt % (TH+2);
            int ld = lt / (TH+2);
            int gx = x0 + lx - 1;
            int gy = y0 + ly - 1;
            int gd = d0 + ld - 1;
            float v = 0.f;
            if (gx >= 0 && gx < W_ && gy >= 0 && gy < H_ && gd >= 0 && gd < D_)
                v = inc[gd*HW_ + gy*W_ + gx];
            tile[li] = v;
        }
        __syncthreads();

        // register-cache the (TD+2)x3x3 neighborhood (compiler may fold back
        // to ds_reads under pressure; CSE keeps unique addresses only)
        float vreg[TD+2][3][3];
        #pragma unroll
        for (int p = 0; p < TD+2; ++p)
            #pragma unroll
            for (int i = 0; i < 3; ++i)
                #pragma unroll
                for (int j = 0; j < 3; ++j)
                    vreg[p][i][j] = tile[(p*(TH+2) + ty + i)*(TW+2) + tx + j];

        const float* wic = wlds + ic*27*OC;
        #pragma unroll
        for (int od = 0; od < TD; ++od)
            #pragma unroll
            for (int kd = 0; kd < 3; ++kd)
                #pragma unroll
                for (int i = 0; i < 3; ++i)
                    #pragma unroll
                    for (int j = 0; j < 3; ++j) {
                        float val = vreg[od + kd][i][j];
                        const float* wp = wic + (kd*9 + i*3 + j)*OC;
                        #pragma unroll
                        for (int oc = 0; oc < OC; ++oc)
                            acc[od][oc] = fmaf(wp[oc], val, acc[od][oc]);
                    }
    }

    #pragma unroll
    for (int od = 0; od < TD; ++od) {
        int obase = (d0 + od)*HW_ + (y0 + ty)*W_ + (x0 + tx);
        #pragma unroll
        for (int oc = 0; oc < OC; ++oc) {
            float r = acc[od][oc];
            if (RELU) r = fmaxf(r, 0.f);
            out[(size_t)oc*DHW_ + obase] = r;
        }
    }
}

// ---------------- softmax over D ------------------------------------------

__global__ __launch_bounds__(256) void softmax_kernel(
        const float* __restrict__ logits, float* __restrict__ out) {
    int pix = blockIdx.x * 256 + threadIdx.x;   // < HW_
    float v[D_];
    float m = -1e30f;
    #pragma unroll
    for (int d = 0; d < D_; ++d) {
        v[d] = logits[d*HW_ + pix];
        m = fmaxf(m, v[d]);
    }
    float s = 0.f;
    #pragma unroll
    for (int d = 0; d < D_; ++d) {
        v[d] = expf(v[d] - m);
        s += v[d];
    }
    float is = 1.f / s;
    #pragma unroll
    for (int d = 0; d < D_; ++d) out[d*HW_ + pix] = v[d] * is;
}

// ---------------- launch ---------------------------------------------------
// ws layout FROZEN (passed rounds 1 & 4):
//   proj @ ws+0 (256 B) | var: 32*DHW f32 (126 MB) | hid: 8*DHW f32 (31.5 MB)
// Total 157,286,656 B. Do NOT add ws allocations (round-3 overflow lesson).

extern "C" void kernel_launch(void* const* d_in, const int* in_sizes, int n_in,
                              void* d_out, int out_size, void* d_ws, size_t ws_size,
                              hipStream_t stream) {
    const float* ref_fea = (const float*)d_in[0];
    const float* src1    = (const float*)d_in[1];
    const float* src2    = (const float*)d_in[2];
    const float* ref_prj = (const float*)d_in[3];
    const float* src_pr1 = (const float*)d_in[4];
    const float* src_pr2 = (const float*)d_in[5];
    const float* depth   = (const float*)d_in[6];
    const float* w1      = (const float*)d_in[7];
    const float* b1      = (const float*)d_in[8];
    const float* w2      = (const float*)d_in[9];
    const float* b2      = (const float*)d_in[10];
    float* out = (float*)d_out;

    char* ws = (char*)d_ws;
    float* proj   = (float*)ws;                                         // 24 f
    float* var    = (float*)(ws + 256);                                 // 126 MB
    float* hid    = (float*)(ws + 256 + (size_t)C_*DHW_*sizeof(float)); // 31.5 MB
    float* logits = var;  // variance region dead after conv1 -> reuse

    proj_setup_kernel<<<1, 64, 0, stream>>>(ref_prj, src_pr1, src_pr2, proj);

    variance_kernel<<<DHW_/256, 256, 0, stream>>>(ref_fea, src1, src2, depth, proj, var);

    dim3 cgrid(W_/32, H_/8, D_/8);   // 5 x 16 x 6 = 480 blocks
    conv3d_kernel<32, 8, true ><<<cgrid, 256, 0, stream>>>(var, w1, b1, hid);
    conv3d_kernel< 8, 1, false><<<cgrid, 256, 0, stream>>>(hid, w2, b2, logits);

    softmax_kernel<<<HW_/256, 256, 0, stream>>>(logits, out);
}

// Round 8
// 357.437 us; speedup vs baseline: 3.0402x; 1.4152x over previous
//
#include <hip/hip_runtime.h>
#include <math.h>

#define C_ 32
#define D_ 48
#define H_ 128
#define W_ 160
#define HW_ (H_*W_)
#define DHW_ (D_*HW_)

// ---------------- small matrix helpers (device, used by 1-thread setup) ----

__device__ __forceinline__ void combine4(const float* p, float* out) {
    #pragma unroll
    for (int i = 0; i < 16; ++i) out[i] = p[i];
    #pragma unroll
    for (int i = 0; i < 3; ++i) {
        #pragma unroll
        for (int j = 0; j < 4; ++j) {
            float s = 0.f;
            #pragma unroll
            for (int k = 0; k < 3; ++k) s += p[16 + i*4 + k] * p[k*4 + j];
            out[i*4 + j] = s;
        }
    }
}

__device__ void inv4(const float* A, float* out) {
    float M[4][8];
    for (int i = 0; i < 4; ++i)
        for (int j = 0; j < 4; ++j) {
            M[i][j] = A[i*4 + j];
            M[i][4 + j] = (i == j) ? 1.f : 0.f;
        }
    for (int c = 0; c < 4; ++c) {
        int piv = c; float best = fabsf(M[c][c]);
        for (int r = c + 1; r < 4; ++r) {
            float a = fabsf(M[r][c]);
            if (a > best) { best = a; piv = r; }
        }
        if (piv != c)
            for (int j = 0; j < 8; ++j) { float t = M[c][j]; M[c][j] = M[piv][j]; M[piv][j] = t; }
        float ip = 1.f / M[c][c];
        for (int j = 0; j < 8; ++j) M[c][j] *= ip;
        for (int r = 0; r < 4; ++r) if (r != c) {
            float f = M[r][c];
            for (int j = 0; j < 8; ++j) M[r][j] -= f * M[c][j];
        }
    }
    for (int i = 0; i < 4; ++i)
        for (int j = 0; j < 4; ++j) out[i*4 + j] = M[i][4 + j];
}

__device__ __forceinline__ void matmul4(const float* A, const float* B, float* Cm) {
    #pragma unroll
    for (int i = 0; i < 4; ++i)
        #pragma unroll
        for (int j = 0; j < 4; ++j) {
            float s = 0.f;
            #pragma unroll
            for (int k = 0; k < 4; ++k) s += A[i*4 + k] * B[k*4 + j];
            Cm[i*4 + j] = s;
        }
}

__global__ void proj_setup_kernel(const float* __restrict__ refp,
                                  const float* __restrict__ sp1,
                                  const float* __restrict__ sp2,
                                  float* __restrict__ proj_out) {
    if (threadIdx.x != 0 || blockIdx.x != 0) return;
    float rc[16], s1[16], s2[16], ri[16], p[16];
    combine4(refp, rc);
    combine4(sp1, s1);
    combine4(sp2, s2);
    inv4(rc, ri);
    for (int v = 0; v < 2; ++v) {
        matmul4(v == 0 ? s1 : s2, ri, p);
        for (int i = 0; i < 3; ++i)
            for (int j = 0; j < 3; ++j) proj_out[v*12 + i*3 + j] = p[i*4 + j];
        for (int i = 0; i < 3; ++i) proj_out[v*12 + 9 + i] = p[i*4 + 3];
    }
}

// ---------------- warp + variance -----------------------------------------

__global__ __launch_bounds__(256) void variance_kernel(
        const float* __restrict__ ref,
        const float* __restrict__ s1g,
        const float* __restrict__ s2g,
        const float* __restrict__ depthv,
        const float* __restrict__ proj,
        float* __restrict__ var) {
    int idx = blockIdx.x * 256 + threadIdx.x;   // < DHW_
    int x = idx % W_;
    int t = idx / W_;
    int y = t % H_;
    float depth = depthv[idx];
    float fx = (float)x, fy = (float)y;

    int off[2][4];
    float wt[2][4];
    #pragma unroll
    for (int v = 0; v < 2; ++v) {
        const float* P = proj + v*12;
        float rx = P[0]*fx + P[1]*fy + P[2];
        float ry = P[3]*fx + P[4]*fy + P[5];
        float rz = P[6]*fx + P[7]*fy + P[8];
        float X = rx*depth + P[9];
        float Y = ry*depth + P[10];
        float Z = rz*depth + P[11];
        float z = (fabsf(Z) < 1e-6f) ? 1e-6f : Z;
        float px = X / z;
        float py = Y / z;
        float x0f = floorf(px), y0f = floorf(py);
        float wx = px - x0f, wy = py - y0f;
        #pragma unroll
        for (int k = 0; k < 4; ++k) {
            float xi = x0f + (float)(k & 1);
            float yi = y0f + (float)(k >> 1);
            bool valid = (xi >= 0.f) && (xi <= (float)(W_-1)) &&
                         (yi >= 0.f) && (yi <= (float)(H_-1));
            int xc = (int)fminf(fmaxf(xi, 0.f), (float)(W_-1));
            int yc = (int)fminf(fmaxf(yi, 0.f), (float)(H_-1));
            off[v][k] = yc * W_ + xc;
            float w = ((k & 1) ? wx : 1.f - wx) * ((k >> 1) ? wy : 1.f - wy);
            wt[v][k] = valid ? w : 0.f;
        }
    }

    int pix = y*W_ + x;
    size_t obase = (size_t)idx;
    const float inv3 = 1.f / 3.f;
    #pragma unroll 4
    for (int c = 0; c < C_; ++c) {
        const float* p1 = s1g + c*HW_;
        const float* p2 = s2g + c*HW_;
        float r = ref[c*HW_ + pix];
        float wv1 = wt[0][0]*p1[off[0][0]] + wt[0][1]*p1[off[0][1]]
                  + wt[0][2]*p1[off[0][2]] + wt[0][3]*p1[off[0][3]];
        float wv2 = wt[1][0]*p2[off[1][0]] + wt[1][1]*p2[off[1][1]]
                  + wt[1][2]*p2[off[1][2]] + wt[1][3]*p2[off[1][3]];
        float s = r + wv1 + wv2;
        float q = r*r + wv1*wv1 + wv2*wv2;
        float m = s * inv3;
        var[(size_t)c*DHW_ + obase] = q*inv3 - m*m;
    }
}

// ---------------- 3D conv, SAME padding, NCDHW ----------------------------
// Block = 32x8 (x,y) plane, TD=4 depth outputs/thread -> grid 960 blocks
// (3.75 blocks/CU; R6's TD=8 gave only 480 = 1.875/CU, occupancy 20%).
// Weights staged once into LDS, layout [(ic*9+ij)*3+kd]*OC+oc, 16B aligned:
// per-(ic,ij) chunk = 3*OC contiguous floats (96B for OC=8 -> ds_read_b128
// mergeable), read wave-uniform -> LDS broadcast (free, m136).
// Tap loop over ij is RUNTIME (#pragma unroll 1): body = 6 column ds_reads
// + 24 weight reads + 96 unrolled FMAs. Live set ~90 VGPR by construction
// -> no rematerialized LDS reads (R6's VGPR=128 pathology).
// Staging address math hoisted (branch-free goff/gmsk, R3 pattern).

template<int IC, int OC, bool RELU>
__global__ __launch_bounds__(256) void conv3d_kernel(
        const float* __restrict__ in,
        const float* __restrict__ wgt,   // (OC, IC, 3,3,3) original layout
        const float* __restrict__ bias,  // (OC)
        float* __restrict__ out) {
    const int TW = 32, TH = 8, TD = 4;
    const int TILE = (TD+2)*(TH+2)*(TW+2);          // 6*10*34 = 2040
    const int PLANE = (TH+2)*(TW+2);                // 340
    const int NW = IC*9*3*OC;                       // conv1 6912, conv2 216
    const int tx = threadIdx.x & 31;
    const int ty = threadIdx.x >> 5;
    const int x0 = blockIdx.x * TW;
    const int y0 = blockIdx.y * TH;
    const int d0 = blockIdx.z * TD;

    __shared__ __attribute__((aligned(16))) float tile[TILE];
    __shared__ __attribute__((aligned(16))) float wlds[NW];

    // one-time: stage weights transposed -> wlds[((ic*9+ij)*3 + kd)*OC + oc]
    for (int t = threadIdx.x; t < NW; t += 256) {
        int oc = t % OC;
        int r  = t / OC;
        int kd = r % 3;
        int g  = r / 3;           // ic*9 + ij
        int ij = g % 9;
        int ic = g / 9;
        wlds[t] = wgt[(oc*IC + ic)*27 + kd*9 + ij];
    }
    // (visible after the __syncthreads() at top of first ic iteration)

    // ---- precompute staging slots (ic-invariant, branch-free) ----
    int   goff[8];
    float gmsk[8];
    #pragma unroll
    for (int k = 0; k < 8; ++k) {
        int s = threadIdx.x + k*256;
        int lx = s % (TW+2);
        int lt = s / (TW+2);
        int ly = lt % (TH+2);
        int ld = lt / (TH+2);
        int gx = x0 + lx - 1;
        int gy = y0 + ly - 1;
        int gd = d0 + ld - 1;
        bool ok = (s < TILE) && gx >= 0 && gx < W_ && gy >= 0 && gy < H_
                             && gd >= 0 && gd < D_;
        goff[k] = ok ? (gd*HW_ + gy*W_ + gx) : 0;
        gmsk[k] = ok ? 1.f : 0.f;
    }

    float acc[TD][OC];
    #pragma unroll
    for (int od = 0; od < TD; ++od)
        #pragma unroll
        for (int oc = 0; oc < OC; ++oc) acc[od][oc] = bias[oc];

    for (int ic = 0; ic < IC; ++ic) {
        const float* inc = in + (size_t)ic * DHW_;
        __syncthreads();
        #pragma unroll
        for (int k = 0; k < 8; ++k) {
            int s = threadIdx.x + k*256;
            if (s < TILE) tile[s] = inc[goff[k]] * gmsk[k];
        }
        __syncthreads();

        const float* wic = wlds + ic*9*3*OC;
        int lbase = ty*(TW+2) + tx;     // (i=0, j=0) tap address
        int jj = 0;
        #pragma unroll 1
        for (int ij = 0; ij < 9; ++ij) {
            float vals[TD+2];
            #pragma unroll
            for (int p = 0; p < TD+2; ++p)
                vals[p] = tile[p*PLANE + lbase];
            const float* wp = wic + ij*3*OC;
            #pragma unroll
            for (int kd = 0; kd < 3; ++kd)
                #pragma unroll
                for (int od = 0; od < TD; ++od) {
                    float v = vals[od + kd];
                    #pragma unroll
                    for (int oc = 0; oc < OC; ++oc)
                        acc[od][oc] = fmaf(wp[kd*OC + oc], v, acc[od][oc]);
                }
            // advance tap: j=0,1,2 then next i row
            if (jj == 2) { jj = 0; lbase += (TW+2) - 2; }
            else         { ++jj; ++lbase; }
        }
    }

    #pragma unroll
    for (int od = 0; od < TD; ++od) {
        int obase = (d0 + od)*HW_ + (y0 + ty)*W_ + (x0 + tx);
        #pragma unroll
        for (int oc = 0; oc < OC; ++oc) {
            float r = acc[od][oc];
            if (RELU) r = fmaxf(r, 0.f);
            out[(size_t)oc*DHW_ + obase] = r;
        }
    }
}

// ---------------- softmax over D ------------------------------------------

__global__ __launch_bounds__(256) void softmax_kernel(
        const float* __restrict__ logits, float* __restrict__ out) {
    int pix = blockIdx.x * 256 + threadIdx.x;   // < HW_
    float v[D_];
    float m = -1e30f;
    #pragma unroll
    for (int d = 0; d < D_; ++d) {
        v[d] = logits[d*HW_ + pix];
        m = fmaxf(m, v[d]);
    }
    float s = 0.f;
    #pragma unroll
    for (int d = 0; d < D_; ++d) {
        v[d] = expf(v[d] - m);
        s += v[d];
    }
    float is = 1.f / s;
    #pragma unroll
    for (int d = 0; d < D_; ++d) out[d*HW_ + pix] = v[d] * is;
}

// ---------------- launch ---------------------------------------------------
// ws layout FROZEN (passed rounds 1, 4, 6):
//   proj @ ws+0 (256 B) | var: 32*DHW f32 (126 MB) | hid: 8*DHW f32 (31.5 MB)
// Total 157,286,656 B. Do NOT add ws allocations (round-3 overflow lesson).

extern "C" void kernel_launch(void* const* d_in, const int* in_sizes, int n_in,
                              void* d_out, int out_size, void* d_ws, size_t ws_size,
                              hipStream_t stream) {
    const float* ref_fea = (const float*)d_in[0];
    const float* src1    = (const float*)d_in[1];
    const float* src2    = (const float*)d_in[2];
    const float* ref_prj = (const float*)d_in[3];
    const float* src_pr1 = (const float*)d_in[4];
    const float* src_pr2 = (const float*)d_in[5];
    const float* depth   = (const float*)d_in[6];
    const float* w1      = (const float*)d_in[7];
    const float* b1      = (const float*)d_in[8];
    const float* w2      = (const float*)d_in[9];
    const float* b2      = (const float*)d_in[10];
    float* out = (float*)d_out;

    char* ws = (char*)d_ws;
    float* proj   = (float*)ws;                                         // 24 f
    float* var    = (float*)(ws + 256);                                 // 126 MB
    float* hid    = (float*)(ws + 256 + (size_t)C_*DHW_*sizeof(float)); // 31.5 MB
    float* logits = var;  // variance region dead after conv1 -> reuse

    proj_setup_kernel<<<1, 64, 0, stream>>>(ref_prj, src_pr1, src_pr2, proj);

    variance_kernel<<<DHW_/256, 256, 0, stream>>>(ref_fea, src1, src2, depth, proj, var);

    dim3 cgrid(W_/32, H_/8, D_/4);   // 5 x 16 x 12 = 960 blocks
    conv3d_kernel<32, 8, true ><<<cgrid, 256, 0, stream>>>(var, w1, b1, hid);
    conv3d_kernel< 8, 1, false><<<cgrid, 256, 0, stream>>>(hid, w2, b2, logits);

    softmax_kernel<<<HW_/256, 256, 0, stream>>>(logits, out);
}

// Round 9
// 342.791 us; speedup vs baseline: 3.1701x; 1.0427x over previous
//
#include <hip/hip_runtime.h>
#include <math.h>

#define C_ 32
#define D_ 48
#define H_ 128
#define W_ 160
#define HW_ (H_*W_)
#define DHW_ (D_*HW_)

// ---------------- small matrix helpers (device, used by 1-thread setup) ----

__device__ __forceinline__ void combine4(const float* p, float* out) {
    #pragma unroll
    for (int i = 0; i < 16; ++i) out[i] = p[i];
    #pragma unroll
    for (int i = 0; i < 3; ++i) {
        #pragma unroll
        for (int j = 0; j < 4; ++j) {
            float s = 0.f;
            #pragma unroll
            for (int k = 0; k < 3; ++k) s += p[16 + i*4 + k] * p[k*4 + j];
            out[i*4 + j] = s;
        }
    }
}

__device__ void inv4(const float* A, float* out) {
    float M[4][8];
    for (int i = 0; i < 4; ++i)
        for (int j = 0; j < 4; ++j) {
            M[i][j] = A[i*4 + j];
            M[i][4 + j] = (i == j) ? 1.f : 0.f;
        }
    for (int c = 0; c < 4; ++c) {
        int piv = c; float best = fabsf(M[c][c]);
        for (int r = c + 1; r < 4; ++r) {
            float a = fabsf(M[r][c]);
            if (a > best) { best = a; piv = r; }
        }
        if (piv != c)
            for (int j = 0; j < 8; ++j) { float t = M[c][j]; M[c][j] = M[piv][j]; M[piv][j] = t; }
        float ip = 1.f / M[c][c];
        for (int j = 0; j < 8; ++j) M[c][j] *= ip;
        for (int r = 0; r < 4; ++r) if (r != c) {
            float f = M[r][c];
            for (int j = 0; j < 8; ++j) M[r][j] -= f * M[c][j];
        }
    }
    for (int i = 0; i < 4; ++i)
        for (int j = 0; j < 4; ++j) out[i*4 + j] = M[i][4 + j];
}

__device__ __forceinline__ void matmul4(const float* A, const float* B, float* Cm) {
    #pragma unroll
    for (int i = 0; i < 4; ++i)
        #pragma unroll
        for (int j = 0; j < 4; ++j) {
            float s = 0.f;
            #pragma unroll
            for (int k = 0; k < 4; ++k) s += A[i*4 + k] * B[k*4 + j];
            Cm[i*4 + j] = s;
        }
}

__global__ void proj_setup_kernel(const float* __restrict__ refp,
                                  const float* __restrict__ sp1,
                                  const float* __restrict__ sp2,
                                  float* __restrict__ proj_out) {
    if (threadIdx.x != 0 || blockIdx.x != 0) return;
    float rc[16], s1[16], s2[16], ri[16], p[16];
    combine4(refp, rc);
    combine4(sp1, s1);
    combine4(sp2, s2);
    inv4(rc, ri);
    for (int v = 0; v < 2; ++v) {
        matmul4(v == 0 ? s1 : s2, ri, p);
        for (int i = 0; i < 3; ++i)
            for (int j = 0; j < 3; ++j) proj_out[v*12 + i*3 + j] = p[i*4 + j];
        for (int i = 0; i < 3; ++i) proj_out[v*12 + 9 + i] = p[i*4 + 3];
    }
}

// ---------------- warp + variance -----------------------------------------

__global__ __launch_bounds__(256) void variance_kernel(
        const float* __restrict__ ref,
        const float* __restrict__ s1g,
        const float* __restrict__ s2g,
        const float* __restrict__ depthv,
        const float* __restrict__ proj,
        float* __restrict__ var) {
    int idx = blockIdx.x * 256 + threadIdx.x;   // < DHW_
    int x = idx % W_;
    int t = idx / W_;
    int y = t % H_;
    float depth = depthv[idx];
    float fx = (float)x, fy = (float)y;

    int off[2][4];
    float wt[2][4];
    #pragma unroll
    for (int v = 0; v < 2; ++v) {
        const float* P = proj + v*12;
        float rx = P[0]*fx + P[1]*fy + P[2];
        float ry = P[3]*fx + P[4]*fy + P[5];
        float rz = P[6]*fx + P[7]*fy + P[8];
        float X = rx*depth + P[9];
        float Y = ry*depth + P[10];
        float Z = rz*depth + P[11];
        float z = (fabsf(Z) < 1e-6f) ? 1e-6f : Z;
        float px = X / z;
        float py = Y / z;
        float x0f = floorf(px), y0f = floorf(py);
        float wx = px - x0f, wy = py - y0f;
        #pragma unroll
        for (int k = 0; k < 4; ++k) {
            float xi = x0f + (float)(k & 1);
            float yi = y0f + (float)(k >> 1);
            bool valid = (xi >= 0.f) && (xi <= (float)(W_-1)) &&
                         (yi >= 0.f) && (yi <= (float)(H_-1));
            int xc = (int)fminf(fmaxf(xi, 0.f), (float)(W_-1));
            int yc = (int)fminf(fmaxf(yi, 0.f), (float)(H_-1));
            off[v][k] = yc * W_ + xc;
            float w = ((k & 1) ? wx : 1.f - wx) * ((k >> 1) ? wy : 1.f - wy);
            wt[v][k] = valid ? w : 0.f;
        }
    }

    int pix = y*W_ + x;
    size_t obase = (size_t)idx;
    const float inv3 = 1.f / 3.f;
    #pragma unroll 4
    for (int c = 0; c < C_; ++c) {
        const float* p1 = s1g + c*HW_;
        const float* p2 = s2g + c*HW_;
        float r = ref[c*HW_ + pix];
        float wv1 = wt[0][0]*p1[off[0][0]] + wt[0][1]*p1[off[0][1]]
                  + wt[0][2]*p1[off[0][2]] + wt[0][3]*p1[off[0][3]];
        float wv2 = wt[1][0]*p2[off[1][0]] + wt[1][1]*p2[off[1][1]]
                  + wt[1][2]*p2[off[1][2]] + wt[1][3]*p2[off[1][3]];
        float s = r + wv1 + wv2;
        float q = r*r + wv1*wv1 + wv2*wv2;
        float m = s * inv3;
        var[(size_t)c*DHW_ + obase] = q*inv3 - m*m;
    }
}

// ---------------- 3D conv, SAME padding, NCDHW ----------------------------
// Block = 32x8 (x,y) plane, TD=4 depth outputs/thread, grid 960 blocks.
// R6 structure (199us): LDS-broadcast weights + runtime ij loop (VGPR 52).
// R8 change: T14 async-stage split. ic+1's 8 staging values are prefetched
// into REGISTERS right after the tile-ready barrier; their first use
// (ds_write) is deferred to after the next barrier, so the ~200-900cyc
// global-load latency lands under the ~1700cyc FMA phase instead of being
// serialized inside the barrier-protected region (R8 counters: VALUBusy
// 56%, HBM 15.6% -> latency-bound staging, the m97 barrier-drain stall).

template<int IC, int OC, bool RELU>
__global__ __launch_bounds__(256) void conv3d_kernel(
        const float* __restrict__ in,
        const float* __restrict__ wgt,   // (OC, IC, 3,3,3) original layout
        const float* __restrict__ bias,  // (OC)
        float* __restrict__ out) {
    const int TW = 32, TH = 8, TD = 4;
    const int TILE = (TD+2)*(TH+2)*(TW+2);          // 6*10*34 = 2040
    const int PLANE = (TH+2)*(TW+2);                // 340
    const int NW = IC*9*3*OC;                       // conv1 6912, conv2 216
    const int tx = threadIdx.x & 31;
    const int ty = threadIdx.x >> 5;
    const int x0 = blockIdx.x * TW;
    const int y0 = blockIdx.y * TH;
    const int d0 = blockIdx.z * TD;

    __shared__ __attribute__((aligned(16))) float tile[TILE];
    __shared__ __attribute__((aligned(16))) float wlds[NW];

    // one-time: stage weights transposed -> wlds[((ic*9+ij)*3 + kd)*OC + oc]
    for (int t = threadIdx.x; t < NW; t += 256) {
        int oc = t % OC;
        int r  = t / OC;
        int kd = r % 3;
        int g  = r / 3;           // ic*9 + ij
        int ij = g % 9;
        int ic = g / 9;
        wlds[t] = wgt[(oc*IC + ic)*27 + kd*9 + ij];
    }
    // (visible after the __syncthreads() at top of first ic iteration)

    // ---- precompute staging slots (ic-invariant, branch-free) ----
    int   goff[8];
    float gmsk[8];
    #pragma unroll
    for (int k = 0; k < 8; ++k) {
        int s = threadIdx.x + k*256;
        int lx = s % (TW+2);
        int lt = s / (TW+2);
        int ly = lt % (TH+2);
        int ld = lt / (TH+2);
        int gx = x0 + lx - 1;
        int gy = y0 + ly - 1;
        int gd = d0 + ld - 1;
        bool ok = (s < TILE) && gx >= 0 && gx < W_ && gy >= 0 && gy < H_
                             && gd >= 0 && gd < D_;
        goff[k] = ok ? (gd*HW_ + gy*W_ + gx) : 0;
        gmsk[k] = ok ? 1.f : 0.f;
    }

    float acc[TD][OC];
    #pragma unroll
    for (int od = 0; od < TD; ++od)
        #pragma unroll
        for (int oc = 0; oc < OC; ++oc) acc[od][oc] = bias[oc];

    // prologue: prefetch ic=0 staging values into registers
    float pre[8];
    #pragma unroll
    for (int k = 0; k < 8; ++k) pre[k] = in[goff[k]] * gmsk[k];

    for (int ic = 0; ic < IC; ++ic) {
        __syncthreads();               // previous compute done reading tile
        #pragma unroll
        for (int k = 0; k < 8; ++k) {
            int s = threadIdx.x + k*256;
            if (s < TILE) tile[s] = pre[k];
        }
        __syncthreads();               // tile ready

        // issue next-ic staging loads NOW; first use is next-iter ds_write,
        // so the latency hides under this iteration's 9-tap FMA phase.
        if (ic + 1 < IC) {
            const float* incn = in + (size_t)(ic + 1) * DHW_;
            #pragma unroll
            for (int k = 0; k < 8; ++k) pre[k] = incn[goff[k]] * gmsk[k];
        }

        const float* wic = wlds + ic*9*3*OC;
        int lbase = ty*(TW+2) + tx;     // (i=0, j=0) tap address
        int jj = 0;
        #pragma unroll 1
        for (int ij = 0; ij < 9; ++ij) {
            float vals[TD+2];
            #pragma unroll
            for (int p = 0; p < TD+2; ++p)
                vals[p] = tile[p*PLANE + lbase];
            const float* wp = wic + ij*3*OC;
            #pragma unroll
            for (int kd = 0; kd < 3; ++kd)
                #pragma unroll
                for (int od = 0; od < TD; ++od) {
                    float v = vals[od + kd];
                    #pragma unroll
                    for (int oc = 0; oc < OC; ++oc)
                        acc[od][oc] = fmaf(wp[kd*OC + oc], v, acc[od][oc]);
                }
            // advance tap: j=0,1,2 then next i row
            if (jj == 2) { jj = 0; lbase += (TW+2) - 2; }
            else         { ++jj; ++lbase; }
        }
    }

    #pragma unroll
    for (int od = 0; od < TD; ++od) {
        int obase = (d0 + od)*HW_ + (y0 + ty)*W_ + (x0 + tx);
        #pragma unroll
        for (int oc = 0; oc < OC; ++oc) {
            float r = acc[od][oc];
            if (RELU) r = fmaxf(r, 0.f);
            out[(size_t)oc*DHW_ + obase] = r;
        }
    }
}

// ---------------- softmax over D ------------------------------------------

__global__ __launch_bounds__(256) void softmax_kernel(
        const float* __restrict__ logits, float* __restrict__ out) {
    int pix = blockIdx.x * 256 + threadIdx.x;   // < HW_
    float v[D_];
    float m = -1e30f;
    #pragma unroll
    for (int d = 0; d < D_; ++d) {
        v[d] = logits[d*HW_ + pix];
        m = fmaxf(m, v[d]);
    }
    float s = 0.f;
    #pragma unroll
    for (int d = 0; d < D_; ++d) {
        v[d] = expf(v[d] - m);
        s += v[d];
    }
    float is = 1.f / s;
    #pragma unroll
    for (int d = 0; d < D_; ++d) out[d*HW_ + pix] = v[d] * is;
}

// ---------------- launch ---------------------------------------------------
// ws layout FROZEN (passed rounds 1, 4, 6, 8):
//   proj @ ws+0 (256 B) | var: 32*DHW f32 (126 MB) | hid: 8*DHW f32 (31.5 MB)
// Total 157,286,656 B. Do NOT add ws allocations (round-3 overflow lesson).

extern "C" void kernel_launch(void* const* d_in, const int* in_sizes, int n_in,
                              void* d_out, int out_size, void* d_ws, size_t ws_size,
                              hipStream_t stream) {
    const float* ref_fea = (const float*)d_in[0];
    const float* src1    = (const float*)d_in[1];
    const float* src2    = (const float*)d_in[2];
    const float* ref_prj = (const float*)d_in[3];
    const float* src_pr1 = (const float*)d_in[4];
    const float* src_pr2 = (const float*)d_in[5];
    const float* depth   = (const float*)d_in[6];
    const float* w1      = (const float*)d_in[7];
    const float* b1      = (const float*)d_in[8];
    const float* w2      = (const float*)d_in[9];
    const float* b2      = (const float*)d_in[10];
    float* out = (float*)d_out;

    char* ws = (char*)d_ws;
    float* proj   = (float*)ws;                                         // 24 f
    float* var    = (float*)(ws + 256);                                 // 126 MB
    float* hid    = (float*)(ws + 256 + (size_t)C_*DHW_*sizeof(float)); // 31.5 MB
    float* logits = var;  // variance region dead after conv1 -> reuse

    proj_setup_kernel<<<1, 64, 0, stream>>>(ref_prj, src_pr1, src_pr2, proj);

    variance_kernel<<<DHW_/256, 256, 0, stream>>>(ref_fea, src1, src2, depth, proj, var);

    dim3 cgrid(W_/32, H_/8, D_/4);   // 5 x 16 x 12 = 960 blocks
    conv3d_kernel<32, 8, true ><<<cgrid, 256, 0, stream>>>(var, w1, b1, hid);
    conv3d_kernel< 8, 1, false><<<cgrid, 256, 0, stream>>>(hid, w2, b2, logits);

    softmax_kernel<<<HW_/256, 256, 0, stream>>>(logits, out);
}

// Round 12
// 331.793 us; speedup vs baseline: 3.2751x; 1.0331x over previous
//
#include <hip/hip_runtime.h>
#include <math.h>

#define C_ 32
#define D_ 48
#define H_ 128
#define W_ 160
#define HW_ (H_*W_)
#define DHW_ (D_*HW_)

// ---------------- small matrix helpers (device, used by 1-thread setup) ----

__device__ __forceinline__ void combine4(const float* p, float* out) {
    #pragma unroll
    for (int i = 0; i < 16; ++i) out[i] = p[i];
    #pragma unroll
    for (int i = 0; i < 3; ++i) {
        #pragma unroll
        for (int j = 0; j < 4; ++j) {
            float s = 0.f;
            #pragma unroll
            for (int k = 0; k < 3; ++k) s += p[16 + i*4 + k] * p[k*4 + j];
            out[i*4 + j] = s;
        }
    }
}

__device__ void inv4(const float* A, float* out) {
    float M[4][8];
    for (int i = 0; i < 4; ++i)
        for (int j = 0; j < 4; ++j) {
            M[i][j] = A[i*4 + j];
            M[i][4 + j] = (i == j) ? 1.f : 0.f;
        }
    for (int c = 0; c < 4; ++c) {
        int piv = c; float best = fabsf(M[c][c]);
        for (int r = c + 1; r < 4; ++r) {
            float a = fabsf(M[r][c]);
            if (a > best) { best = a; piv = r; }
        }
        if (piv != c)
            for (int j = 0; j < 8; ++j) { float t = M[c][j]; M[c][j] = M[piv][j]; M[piv][j] = t; }
        float ip = 1.f / M[c][c];
        for (int j = 0; j < 8; ++j) M[c][j] *= ip;
        for (int r = 0; r < 4; ++r) if (r != c) {
            float f = M[r][c];
            for (int j = 0; j < 8; ++j) M[r][j] -= f * M[c][j];
        }
    }
    for (int i = 0; i < 4; ++i)
        for (int j = 0; j < 4; ++j) out[i*4 + j] = M[i][4 + j];
}

__device__ __forceinline__ void matmul4(const float* A, const float* B, float* Cm) {
    #pragma unroll
    for (int i = 0; i < 4; ++i)
        #pragma unroll
        for (int j = 0; j < 4; ++j) {
            float s = 0.f;
            #pragma unroll
            for (int k = 0; k < 4; ++k) s += A[i*4 + k] * B[k*4 + j];
            Cm[i*4 + j] = s;
        }
}

__global__ void proj_setup_kernel(const float* __restrict__ refp,
                                  const float* __restrict__ sp1,
                                  const float* __restrict__ sp2,
                                  float* __restrict__ proj_out) {
    if (threadIdx.x != 0 || blockIdx.x != 0) return;
    float rc[16], s1[16], s2[16], ri[16], p[16];
    combine4(refp, rc);
    combine4(sp1, s1);
    combine4(sp2, s2);
    inv4(rc, ri);
    for (int v = 0; v < 2; ++v) {
        matmul4(v == 0 ? s1 : s2, ri, p);
        for (int i = 0; i < 3; ++i)
            for (int j = 0; j < 3; ++j) proj_out[v*12 + i*3 + j] = p[i*4 + j];
        for (int i = 0; i < 3; ++i) proj_out[v*12 + 9 + i] = p[i*4 + 3];
    }
}

// ---------------- warp + variance -----------------------------------------

__global__ __launch_bounds__(256) void variance_kernel(
        const float* __restrict__ ref,
        const float* __restrict__ s1g,
        const float* __restrict__ s2g,
        const float* __restrict__ depthv,
        const float* __restrict__ proj,
        float* __restrict__ var) {
    int idx = blockIdx.x * 256 + threadIdx.x;   // < DHW_
    int x = idx % W_;
    int t = idx / W_;
    int y = t % H_;
    float depth = depthv[idx];
    float fx = (float)x, fy = (float)y;

    int off[2][4];
    float wt[2][4];
    #pragma unroll
    for (int v = 0; v < 2; ++v) {
        const float* P = proj + v*12;
        float rx = P[0]*fx + P[1]*fy + P[2];
        float ry = P[3]*fx + P[4]*fy + P[5];
        float rz = P[6]*fx + P[7]*fy + P[8];
        float X = rx*depth + P[9];
        float Y = ry*depth + P[10];
        float Z = rz*depth + P[11];
        float z = (fabsf(Z) < 1e-6f) ? 1e-6f : Z;
        float px = X / z;
        float py = Y / z;
        float x0f = floorf(px), y0f = floorf(py);
        float wx = px - x0f, wy = py - y0f;
        #pragma unroll
        for (int k = 0; k < 4; ++k) {
            float xi = x0f + (float)(k & 1);
            float yi = y0f + (float)(k >> 1);
            bool valid = (xi >= 0.f) && (xi <= (float)(W_-1)) &&
                         (yi >= 0.f) && (yi <= (float)(H_-1));
            int xc = (int)fminf(fmaxf(xi, 0.f), (float)(W_-1));
            int yc = (int)fminf(fmaxf(yi, 0.f), (float)(H_-1));
            off[v][k] = yc * W_ + xc;
            float w = ((k & 1) ? wx : 1.f - wx) * ((k >> 1) ? wy : 1.f - wy);
            wt[v][k] = valid ? w : 0.f;
        }
    }

    int pix = y*W_ + x;
    size_t obase = (size_t)idx;
    const float inv3 = 1.f / 3.f;
    #pragma unroll 4
    for (int c = 0; c < C_; ++c) {
        const float* p1 = s1g + c*HW_;
        const float* p2 = s2g + c*HW_;
        float r = ref[c*HW_ + pix];
        float wv1 = wt[0][0]*p1[off[0][0]] + wt[0][1]*p1[off[0][1]]
                  + wt[0][2]*p1[off[0][2]] + wt[0][3]*p1[off[0][3]];
        float wv2 = wt[1][0]*p2[off[1][0]] + wt[1][1]*p2[off[1][1]]
                  + wt[1][2]*p2[off[1][2]] + wt[1][3]*p2[off[1][3]];
        float s = r + wv1 + wv2;
        float q = r*r + wv1*wv1 + wv2*wv2;
        float m = s * inv3;
        var[(size_t)c*DHW_ + obase] = q*inv3 - m*m;
    }
}

// ---------------- 3D conv, SAME padding, NCDHW ----------------------------
// R9 post-mortem: conv1 is LDS-PIPE BOUND (per-ic per-wave: 54 b32 values +
// 54 b128 weight-broadcasts = 961 cyc -> model 192us vs measured 189us).
// Weight reads are od-independent -> TD=8 halves their per-output cost:
// per ij = 10 b32 + 6 b128 = 130 cyc feeding 192 FMAs. Model ~125us.
// R6's TD=8 failure was the UNROLLED ij + vreg[6][3][3] cache (VGPR 128,
// rematerialization); the runtime-ij loop keeps the live set ~115 VGPR.
// Weights in LDS [(ic*9+ij)*3+kd]*OC+oc (proven), tile [d][y][x] (stride-1
// x across lanes, conflict-free), T14 register prefetch (proven +10us).

template<int IC, int OC, int TD, bool RELU>
__global__ __launch_bounds__(256) void conv3d_kernel(
        const float* __restrict__ in,
        const float* __restrict__ wgt,   // (OC, IC, 3,3,3) original layout
        const float* __restrict__ bias,  // (OC)
        float* __restrict__ out) {
    const int TW = 32, TH = 8;
    const int TILE = (TD+2)*(TH+2)*(TW+2);          // TD=8: 10*10*34 = 3400
    const int PLANE = (TH+2)*(TW+2);                // 340
    const int LOADS = (TILE + 255) / 256;           // TD=8: 14
    const int NW = IC*9*3*OC;                       // conv1 6912, conv2 216
    const int tx = threadIdx.x & 31;
    const int ty = threadIdx.x >> 5;
    const int x0 = blockIdx.x * TW;
    const int y0 = blockIdx.y * TH;
    const int d0 = blockIdx.z * TD;

    __shared__ __attribute__((aligned(16))) float tile[TILE];
    __shared__ __attribute__((aligned(16))) float wlds[NW];

    // one-time: stage weights transposed -> wlds[((ic*9+ij)*3 + kd)*OC + oc]
    for (int t = threadIdx.x; t < NW; t += 256) {
        int oc = t % OC;
        int r  = t / OC;
        int kd = r % 3;
        int g  = r / 3;           // ic*9 + ij
        int ij = g % 9;
        int ic = g / 9;
        wlds[t] = wgt[(oc*IC + ic)*27 + kd*9 + ij];
    }
    // (visible after the __syncthreads() at top of first ic iteration)

    // ---- precompute staging slots (ic-invariant, branch-free) ----
    int   goff[LOADS];
    float gmsk[LOADS];
    #pragma unroll
    for (int k = 0; k < LOADS; ++k) {
        int s = threadIdx.x + k*256;
        int lx = s % (TW+2);
        int lt = s / (TW+2);
        int ly = lt % (TH+2);
        int ld = lt / (TH+2);
        int gx = x0 + lx - 1;
        int gy = y0 + ly - 1;
        int gd = d0 + ld - 1;
        bool ok = (s < TILE) && gx >= 0 && gx < W_ && gy >= 0 && gy < H_
                             && gd >= 0 && gd < D_;
        goff[k] = ok ? (gd*HW_ + gy*W_ + gx) : 0;
        gmsk[k] = ok ? 1.f : 0.f;
    }

    float acc[TD][OC];
    #pragma unroll
    for (int od = 0; od < TD; ++od)
        #pragma unroll
        for (int oc = 0; oc < OC; ++oc) acc[od][oc] = bias[oc];

    // prologue: prefetch ic=0 staging values into registers
    float pre[LOADS];
    #pragma unroll
    for (int k = 0; k < LOADS; ++k) pre[k] = in[goff[k]] * gmsk[k];

    for (int ic = 0; ic < IC; ++ic) {
        __syncthreads();               // previous compute done reading tile
        #pragma unroll
        for (int k = 0; k < LOADS; ++k) {
            int s = threadIdx.x + k*256;
            if (s < TILE) tile[s] = pre[k];
        }
        __syncthreads();               // tile ready

        // issue next-ic staging loads NOW; first use is next-iter ds_write,
        // so the latency hides under this iteration's 9-tap FMA phase.
        if (ic + 1 < IC) {
            const float* incn = in + (size_t)(ic + 1) * DHW_;
            #pragma unroll
            for (int k = 0; k < LOADS; ++k) pre[k] = incn[goff[k]] * gmsk[k];
        }

        const float* wic = wlds + ic*9*3*OC;
        int lbase = ty*(TW+2) + tx;     // (i=0, j=0) tap address
        int jj = 0;
        #pragma unroll 1
        for (int ij = 0; ij < 9; ++ij) {
            float vals[TD+2];
            #pragma unroll
            for (int p = 0; p < TD+2; ++p)
                vals[p] = tile[p*PLANE + lbase];
            const float* wp = wic + ij*3*OC;
            #pragma unroll
            for (int kd = 0; kd < 3; ++kd)
                #pragma unroll
                for (int od = 0; od < TD; ++od) {
                    float v = vals[od + kd];
                    #pragma unroll
                    for (int oc = 0; oc < OC; ++oc)
                        acc[od][oc] = fmaf(wp[kd*OC + oc], v, acc[od][oc]);
                }
            // advance tap: j=0,1,2 then next i row
            if (jj == 2) { jj = 0; lbase += (TW+2) - 2; }
            else         { ++jj; ++lbase; }
        }
    }

    #pragma unroll
    for (int od = 0; od < TD; ++od) {
        int obase = (d0 + od)*HW_ + (y0 + ty)*W_ + (x0 + tx);
        #pragma unroll
        for (int oc = 0; oc < OC; ++oc) {
            float r = acc[od][oc];
            if (RELU) r = fmaxf(r, 0.f);
            out[(size_t)oc*DHW_ + obase] = r;
        }
    }
}

// ---------------- softmax over D ------------------------------------------

__global__ __launch_bounds__(256) void softmax_kernel(
        const float* __restrict__ logits, float* __restrict__ out) {
    int pix = blockIdx.x * 256 + threadIdx.x;   // < HW_
    float v[D_];
    float m = -1e30f;
    #pragma unroll
    for (int d = 0; d < D_; ++d) {
        v[d] = logits[d*HW_ + pix];
        m = fmaxf(m, v[d]);
    }
    float s = 0.f;
    #pragma unroll
    for (int d = 0; d < D_; ++d) {
        v[d] = expf(v[d] - m);
        s += v[d];
    }
    float is = 1.f / s;
    #pragma unroll
    for (int d = 0; d < D_; ++d) out[d*HW_ + pix] = v[d] * is;
}

// ---------------- launch ---------------------------------------------------
// ws layout FROZEN (passed rounds 1, 4, 6, 8, 9):
//   proj @ ws+0 (256 B) | var: 32*DHW f32 (126 MB) | hid: 8*DHW f32 (31.5 MB)
// Total 157,286,656 B. Do NOT add ws allocations (round-3 overflow lesson).

extern "C" void kernel_launch(void* const* d_in, const int* in_sizes, int n_in,
                              void* d_out, int out_size, void* d_ws, size_t ws_size,
                              hipStream_t stream) {
    const float* ref_fea = (const float*)d_in[0];
    const float* src1    = (const float*)d_in[1];
    const float* src2    = (const float*)d_in[2];
    const float* ref_prj = (const float*)d_in[3];
    const float* src_pr1 = (const float*)d_in[4];
    const float* src_pr2 = (const float*)d_in[5];
    const float* depth   = (const float*)d_in[6];
    const float* w1      = (const float*)d_in[7];
    const float* b1      = (const float*)d_in[8];
    const float* w2      = (const float*)d_in[9];
    const float* b2      = (const float*)d_in[10];
    float* out = (float*)d_out;

    char* ws = (char*)d_ws;
    float* proj   = (float*)ws;                                         // 24 f
    float* var    = (float*)(ws + 256);                                 // 126 MB
    float* hid    = (float*)(ws + 256 + (size_t)C_*DHW_*sizeof(float)); // 31.5 MB
    float* logits = var;  // variance region dead after conv1 -> reuse

    proj_setup_kernel<<<1, 64, 0, stream>>>(ref_prj, src_pr1, src_pr2, proj);

    variance_kernel<<<DHW_/256, 256, 0, stream>>>(ref_fea, src1, src2, depth, proj, var);

    dim3 cgrid(W_/32, H_/8, D_/8);   // 5 x 16 x 6 = 480 blocks
    conv3d_kernel<32, 8, 8, true ><<<cgrid, 256, 0, stream>>>(var, w1, b1, hid);
    conv3d_kernel< 8, 1, 8, false><<<cgrid, 256, 0, stream>>>(hid, w2, b2, logits);

    softmax_kernel<<<HW_/256, 256, 0, stream>>>(logits, out);
}